// Round 14
// baseline (794.136 us; speedup 1.0000x reference)
//
#include <hip/hip_runtime.h>
#include <math.h>

#define NAUTH 100000
#define NPAP  200000
#define DIM   128
#define ELIKE 600000
#define ECO   600000
#define BATCH 16384
#define EPSW  1e-8f

static_assert(ELIKE == ECO, "degree kernel assumes equal edge counts");

// ===========================================================================
// Stage 1: integer degree histograms.
// ===========================================================================
__global__ __launch_bounds__(256) void degree_kernel(
    const int* __restrict__ like_src, const int* __restrict__ like_dst,
    const int* __restrict__ co_src,   const int* __restrict__ co_dst,
    int* __restrict__ deg_ls, int* __restrict__ deg_ld,
    int* __restrict__ deg_cs, int* __restrict__ deg_cd)
{
    int stride = gridDim.x * blockDim.x;
    for (int i = blockIdx.x * blockDim.x + threadIdx.x; i < ELIKE; i += stride) {
        atomicAdd(&deg_ls[like_src[i]], 1);
        atomicAdd(&deg_ld[like_dst[i]], 1);
        atomicAdd(&deg_cs[co_src[i]],   1);
        atomicAdd(&deg_cd[co_dst[i]],   1);
    }
}

// ===========================================================================
// Stage 2: 3-stage exclusive scan of a degree array -> segment cursors.
// ===========================================================================
#define SCAN_CHUNK 1024

__global__ __launch_bounds__(256) void scan_block_sums(
    const int* __restrict__ deg, int* __restrict__ bsum, int n)
{
    __shared__ int sd[256];
    int t = threadIdx.x;
    int base = blockIdx.x * SCAN_CHUNK + t * 4;
    int s = 0;
    #pragma unroll
    for (int j = 0; j < 4; ++j) { int idx = base + j; if (idx < n) s += deg[idx]; }
    sd[t] = s; __syncthreads();
    for (int o = 128; o > 0; o >>= 1) { if (t < o) sd[t] += sd[t + o]; __syncthreads(); }
    if (t == 0) bsum[blockIdx.x] = sd[0];
}

__global__ void scan_serial(int* __restrict__ bsum, int nb)
{
    if (threadIdx.x == 0 && blockIdx.x == 0) {
        int run = 0;
        for (int i = 0; i < nb; ++i) { int v = bsum[i]; bsum[i] = run; run += v; }
    }
}

__global__ __launch_bounds__(256) void scan_write_cur(
    const int* __restrict__ deg, const int* __restrict__ bsum,
    int* __restrict__ cur, int n)
{
    __shared__ int sd[256];
    int t = threadIdx.x;
    int base = blockIdx.x * SCAN_CHUNK + t * 4;
    int d[4]; int s = 0;
    #pragma unroll
    for (int j = 0; j < 4; ++j) {
        int idx = base + j;
        d[j] = (idx < n) ? deg[idx] : 0;
        s += d[j];
    }
    sd[t] = s; __syncthreads();
    for (int o = 1; o < 256; o <<= 1) {
        int v = (t >= o) ? sd[t - o] : 0;
        __syncthreads();
        sd[t] += v;
        __syncthreads();
    }
    int excl = sd[t] - s + bsum[blockIdx.x];
    #pragma unroll
    for (int j = 0; j < 4; ++j) {
        int idx = base + j;
        if (idx < n) { cur[idx] = excl; excl += d[j]; }
    }
}

// ===========================================================================
// Stage 3: counting-sort placement with inline coef computation.
// After this kernel, cur[n] == segment_end(n); start = cur[n] - deg[n].
// ===========================================================================
__global__ __launch_bounds__(256) void placement_kernel(
    const int* __restrict__ like_src, const int* __restrict__ like_dst,
    const int* __restrict__ co_src,   const int* __restrict__ co_dst,
    const int* __restrict__ deg_ls, const int* __restrict__ deg_ld,
    const int* __restrict__ deg_cs, const int* __restrict__ deg_cd,
    int* __restrict__ cur_ls, int* __restrict__ cur_ld, int* __restrict__ cur_cd,
    int2* __restrict__ pairs_ls, int2* __restrict__ pairs_ld,
    int2* __restrict__ pairs_cd)
{
    int stride = gridDim.x * blockDim.x;
    for (int i = blockIdx.x * blockDim.x + threadIdx.x; i < ELIKE; i += stride) {
        int ls = like_src[i], ld = like_dst[i];
        float lc = 1.0f / sqrtf(fmaxf((float)deg_ls[ls] * (float)deg_ld[ld], 1.0f));
        int lcb = __float_as_int(lc);
        int s1 = atomicAdd(&cur_ls[ls], 1);
        pairs_ls[s1] = make_int2(ld, lcb);          // by like_src, gather paper
        int s2 = atomicAdd(&cur_ld[ld], 1);
        pairs_ld[s2] = make_int2(ls, lcb);          // by like_dst, gather author

        int cs = co_src[i], cd = co_dst[i];
        float cc = 1.0f / sqrtf(fmaxf((float)deg_cs[cs] * (float)deg_cd[cd], 1.0f));
        int s3 = atomicAdd(&cur_cd[cd], 1);
        pairs_cd[s3] = make_int2(cs, __float_as_int(cc)); // by co_dst, gather author
    }
}

// ===========================================================================
// Segmented gather v3: half-wave float4 rows; pair {gidx,coef} loaded
// DIRECTLY at a half-uniform address (HW broadcast, L1-cached, no shfl ->
// gather addresses computable far ahead of use); 4 independent accumulator
// chains per half (edges k+half, k+2+half, k+4+half, k+6+half; stride 8)
// -> 8 gather loads in flight per wave. Tails predicated per chain.
// ===========================================================================
__device__ __forceinline__ void seg_acc8(
    const int2* __restrict__ pairs, int start, int end,
    int half, int sub, const float* __restrict__ src,
    float4& a0, float4& a1, float4& a2, float4& a3)
{
    for (int k = start; k < end; k += 8) {
        int k0 = k + half;
        int k1 = k + 2 + half;
        int k2 = k + 4 + half;
        int k3 = k + 6 + half;
        if (k0 < end) {
            int2 p = pairs[k0]; float c = __int_as_float(p.y);
            float4 v = ((const float4*)(src + (size_t)p.x * DIM))[sub];
            a0.x += v.x * c; a0.y += v.y * c; a0.z += v.z * c; a0.w += v.w * c;
        }
        if (k1 < end) {
            int2 p = pairs[k1]; float c = __int_as_float(p.y);
            float4 v = ((const float4*)(src + (size_t)p.x * DIM))[sub];
            a1.x += v.x * c; a1.y += v.y * c; a1.z += v.z * c; a1.w += v.w * c;
        }
        if (k2 < end) {
            int2 p = pairs[k2]; float c = __int_as_float(p.y);
            float4 v = ((const float4*)(src + (size_t)p.x * DIM))[sub];
            a2.x += v.x * c; a2.y += v.y * c; a2.z += v.z * c; a2.w += v.w * c;
        }
        if (k3 < end) {
            int2 p = pairs[k3]; float c = __int_as_float(p.y);
            float4 v = ((const float4*)(src + (size_t)p.x * DIM))[sub];
            a3.x += v.x * c; a3.y += v.y * c; a3.z += v.z * c; a3.w += v.w * c;
        }
    }
}

// combine 4 chains + cross-half reduce; both halves end with the total
__device__ __forceinline__ float4 quad_xh_reduce(float4 a0, float4 a1,
                                                 float4 a2, float4 a3)
{
    float4 r;
    r.x = (a0.x + a1.x) + (a2.x + a3.x);
    r.y = (a0.y + a1.y) + (a2.y + a3.y);
    r.z = (a0.z + a1.z) + (a2.z + a3.z);
    r.w = (a0.w + a1.w) + (a2.w + a3.w);
    r.x += __shfl_xor(r.x, 32);
    r.y += __shfl_xor(r.y, 32);
    r.z += __shfl_xor(r.z, 32);
    r.w += __shfl_xor(r.w, 32);
    return r;
}

// ===========================================================================
// Layer-1 fused kernel (authors AND papers in one grid, node-range split):
//   author n : co_a1[n] = sum(co);  wr_a1[n] = u_sw*emb + sum(like by src)
//   paper  n : wr_p1[n] = i_sw*emb + sum(like by dst)
// ===========================================================================
__global__ __launch_bounds__(256) void l1_kernel(
    const float* __restrict__ author_emb, const float* __restrict__ paper_emb,
    const int* __restrict__ cur_cd, const int* __restrict__ deg_cd,
    const int2* __restrict__ pairs_cd,
    const int* __restrict__ cur_ls, const int* __restrict__ deg_ls,
    const int2* __restrict__ pairs_ls,
    const int* __restrict__ cur_ld, const int* __restrict__ deg_ld,
    const int2* __restrict__ pairs_ld,
    float* __restrict__ co_a1, float* __restrict__ wr_a1,
    float* __restrict__ wr_p1)
{
    int lane = threadIdx.x & 63;
    int half = lane >> 5;
    int sub  = lane & 31;
    int wid  = blockIdx.x * (blockDim.x >> 6) + (threadIdx.x >> 6);

    if (wid < NAUTH) {
        int n = wid;
        float4 z = make_float4(0.f,0.f,0.f,0.f);
        float4 c0 = z, c1 = z, c2 = z, c3 = z;
        int ec = cur_cd[n], dc = deg_cd[n];
        seg_acc8(pairs_cd, ec - dc, ec, half, sub, author_emb, c0, c1, c2, c3);
        float4 cacc = quad_xh_reduce(c0, c1, c2, c3);

        float4 w0 = z, w1 = z, w2 = z, w3 = z;
        int el = cur_ls[n], dl = deg_ls[n];
        seg_acc8(pairs_ls, el - dl, el, half, sub, paper_emb, w0, w1, w2, w3);
        float4 wacc = quad_xh_reduce(w0, w1, w2, w3);

        if (half == 0) {
            float d  = (float)dl;
            float sw = 1.0f - d / (d + EPSW);
            float4 base = ((const float4*)(author_emb + (size_t)n * DIM))[sub];
            float4 wr;
            wr.x = sw * base.x + wacc.x;
            wr.y = sw * base.y + wacc.y;
            wr.z = sw * base.z + wacc.z;
            wr.w = sw * base.w + wacc.w;
            ((float4*)(co_a1 + (size_t)n * DIM))[sub] = cacc;
            ((float4*)(wr_a1 + (size_t)n * DIM))[sub] = wr;
        }
    } else {
        int n = wid - NAUTH;
        if (n >= NPAP) return;
        float4 z = make_float4(0.f,0.f,0.f,0.f);
        float4 p0 = z, p1 = z, p2 = z, p3 = z;
        int e = cur_ld[n], dg = deg_ld[n];
        seg_acc8(pairs_ld, e - dg, e, half, sub, author_emb, p0, p1, p2, p3);
        float4 acc = quad_xh_reduce(p0, p1, p2, p3);

        if (half == 0) {
            float d  = (float)dg;
            float sw = 1.0f - d / (d + EPSW);
            float4 base = ((const float4*)(paper_emb + (size_t)n * DIM))[sub];
            acc.x += sw * base.x;
            acc.y += sw * base.y;
            acc.z += sw * base.z;
            acc.w += sw * base.w;
            ((float4*)(wr_p1 + (size_t)n * DIM))[sub] = acc;
        }
    }
}

// ===========================================================================
// Layer-2 author pass (fused, *0.5 folded):
//   a2buf[n] = 0.5*( u_sw*wr_a1[n] + sum(co: co_a1) + sum(like: wr_p1) )
// ===========================================================================
__global__ __launch_bounds__(256) void l2_author_kernel(
    const float* __restrict__ co_a1, const float* __restrict__ wr_a1,
    const float* __restrict__ wr_p1,
    const int* __restrict__ cur_cd, const int* __restrict__ deg_cd,
    const int2* __restrict__ pairs_cd,
    const int* __restrict__ cur_ls, const int* __restrict__ deg_ls,
    const int2* __restrict__ pairs_ls,
    float* __restrict__ a2buf)
{
    int lane = threadIdx.x & 63;
    int half = lane >> 5;
    int sub  = lane & 31;
    int n = blockIdx.x * (blockDim.x >> 6) + (threadIdx.x >> 6);
    if (n >= NAUTH) return;

    float4 z = make_float4(0.f,0.f,0.f,0.f);
    float4 a0 = z, a1 = z, a2 = z, a3 = z;
    int ec = cur_cd[n], dc = deg_cd[n];
    seg_acc8(pairs_cd, ec - dc, ec, half, sub, co_a1, a0, a1, a2, a3);
    int el = cur_ls[n], dl = deg_ls[n];
    seg_acc8(pairs_ls, el - dl, el, half, sub, wr_p1, a0, a1, a2, a3);

    float4 acc = quad_xh_reduce(a0, a1, a2, a3);
    if (half == 0) {
        float d  = (float)dl;
        float sw = 1.0f - d / (d + EPSW);
        float4 base = ((const float4*)(wr_a1 + (size_t)n * DIM))[sub];
        acc.x = 0.5f * (acc.x + sw * base.x);
        acc.y = 0.5f * (acc.y + sw * base.y);
        acc.z = 0.5f * (acc.z + sw * base.z);
        acc.w = 0.5f * (acc.w + sw * base.w);
        ((float4*)(a2buf + (size_t)n * DIM))[sub] = acc;
    }
}

// ===========================================================================
// Final scoring: one wave per batch element; full final_author never built.
// ===========================================================================
__global__ __launch_bounds__(256) void final_kernel(
    const float* __restrict__ author_emb, const float* __restrict__ paper_emb,
    const int* __restrict__ authors, const int* __restrict__ papers,
    const float* __restrict__ co_a1, const float* __restrict__ wr_a1,
    const float* __restrict__ a2buf,
    float* __restrict__ out_pred, float* __restrict__ out_a, float* __restrict__ out_p)
{
    int lane  = threadIdx.x & 63;
    int wpb   = blockDim.x >> 6;
    int wave0 = blockIdx.x * wpb + (threadIdx.x >> 6);
    int wstr  = gridDim.x * wpb;
    for (int b = wave0; b < BATCH; b += wstr) {
        int a = authors[b];
        int p = papers[b];
        size_t arow = (size_t)a * DIM;
        size_t prow = (size_t)p * DIM;
        float2 e  = ((const float2*)(author_emb + arow))[lane];
        float2 c1 = ((const float2*)(co_a1 + arow))[lane];
        float2 w1 = ((const float2*)(wr_a1 + arow))[lane];
        float2 a2 = ((const float2*)(a2buf + arow))[lane];
        float fx = e.x + 0.5f * c1.x + 0.5f * w1.x + a2.x;
        float fy = e.y + 0.5f * c1.y + 0.5f * w1.y + a2.y;
        float2 pp = ((const float2*)(paper_emb + prow))[lane];
        ((float2*)(out_a + (size_t)b * DIM))[lane] = make_float2(fx, fy);
        ((float2*)(out_p + (size_t)b * DIM))[lane] = pp;
        float dot = fx * pp.x + fy * pp.y;
        #pragma unroll
        for (int off = 32; off; off >>= 1) dot += __shfl_xor(dot, off);
        if (lane == 0) out_pred[b] = 1.0f / (1.0f + expf(-dot));
    }
}

extern "C" void kernel_launch(void* const* d_in, const int* in_sizes, int n_in,
                              void* d_out, int out_size, void* d_ws, size_t ws_size,
                              hipStream_t stream) {
    const float* author_emb = (const float*)d_in[0];
    const float* paper_emb  = (const float*)d_in[1];
    const int*   authors    = (const int*)d_in[2];
    const int*   papers     = (const int*)d_in[3];
    const int*   like_src   = (const int*)d_in[4];
    const int*   like_dst   = (const int*)d_in[5];
    const int*   co_src     = (const int*)d_in[6];
    const int*   co_dst     = (const int*)d_in[7];

    // ---- workspace carve-up (256B aligned) ----
    size_t off = 0;
    auto alloc = [&](size_t bytes) -> void* {
        void* p = (char*)d_ws + off;
        off += (bytes + 255) & ~(size_t)255;
        return p;
    };
    int* deg_ls = (int*)alloc((size_t)NAUTH * 4);
    int* deg_ld = (int*)alloc((size_t)NPAP  * 4);
    int* deg_cs = (int*)alloc((size_t)NAUTH * 4);
    int* deg_cd = (int*)alloc((size_t)NAUTH * 4);
    size_t deg_bytes = off;

    int* cur_ls = (int*)alloc((size_t)NAUTH * 4);
    int* cur_ld = (int*)alloc((size_t)NPAP  * 4);
    int* cur_cd = (int*)alloc((size_t)NAUTH * 4);
    int* bsum_ls = (int*)alloc(1024);
    int* bsum_ld = (int*)alloc(1024);
    int* bsum_cd = (int*)alloc(1024);
    int2* pairs_ls = (int2*)alloc((size_t)ELIKE * 8);
    int2* pairs_ld = (int2*)alloc((size_t)ELIKE * 8);
    int2* pairs_cd = (int2*)alloc((size_t)ECO   * 8);

    float* co_a1 = (float*)alloc((size_t)NAUTH * DIM * 4);
    float* wr_a1 = (float*)alloc((size_t)NAUTH * DIM * 4);
    float* wr_p1 = (float*)alloc((size_t)NPAP  * DIM * 4);
    float* a2buf = (float*)alloc((size_t)NAUTH * DIM * 4);

    float* out_pred = (float*)d_out;               // [B]
    float* out_a    = out_pred + BATCH;            // [B,D]
    float* out_p    = out_a + (size_t)BATCH * DIM; // [B,D]

    const int nb_ls = (NAUTH + SCAN_CHUNK - 1) / SCAN_CHUNK;  // 98
    const int nb_ld = (NPAP  + SCAN_CHUNK - 1) / SCAN_CHUNK;  // 196
    const int nb_cd = nb_ls;

    // ---- degrees ----
    hipMemsetAsync(d_ws, 0, deg_bytes, stream);
    degree_kernel<<<2344, 256, 0, stream>>>(like_src, like_dst, co_src, co_dst,
                                            deg_ls, deg_ld, deg_cs, deg_cd);

    // ---- exclusive scans -> cursors ----
    scan_block_sums<<<nb_ls, 256, 0, stream>>>(deg_ls, bsum_ls, NAUTH);
    scan_block_sums<<<nb_ld, 256, 0, stream>>>(deg_ld, bsum_ld, NPAP);
    scan_block_sums<<<nb_cd, 256, 0, stream>>>(deg_cd, bsum_cd, NAUTH);
    scan_serial<<<1, 64, 0, stream>>>(bsum_ls, nb_ls);
    scan_serial<<<1, 64, 0, stream>>>(bsum_ld, nb_ld);
    scan_serial<<<1, 64, 0, stream>>>(bsum_cd, nb_cd);
    scan_write_cur<<<nb_ls, 256, 0, stream>>>(deg_ls, bsum_ls, cur_ls, NAUTH);
    scan_write_cur<<<nb_ld, 256, 0, stream>>>(deg_ld, bsum_ld, cur_ld, NPAP);
    scan_write_cur<<<nb_cd, 256, 0, stream>>>(deg_cd, bsum_cd, cur_cd, NAUTH);

    // ---- counting-sort placement (coefs computed inline) ----
    placement_kernel<<<2344, 256, 0, stream>>>(like_src, like_dst, co_src, co_dst,
                                               deg_ls, deg_ld, deg_cs, deg_cd,
                                               cur_ls, cur_ld, cur_cd,
                                               pairs_ls, pairs_ld, pairs_cd);

    // ---- layer 1 (merged author+paper grid; gather engine v3) ----
    l1_kernel<<<(NAUTH + NPAP + 3) / 4, 256, 0, stream>>>(
        author_emb, paper_emb,
        cur_cd, deg_cd, pairs_cd,
        cur_ls, deg_ls, pairs_ls,
        cur_ld, deg_ld, pairs_ld,
        co_a1, wr_a1, wr_p1);

    // ---- layer 2 (fused author pass; 0.5 folded; _wr_p2 dead) ----
    l2_author_kernel<<<(NAUTH + 3) / 4, 256, 0, stream>>>(
        co_a1, wr_a1, wr_p1,
        cur_cd, deg_cd, pairs_cd, cur_ls, deg_ls, pairs_ls,
        a2buf);

    // ---- scoring ----
    final_kernel<<<4096, 256, 0, stream>>>(author_emb, paper_emb, authors, papers,
                                           co_a1, wr_a1, a2buf,
                                           out_pred, out_a, out_p);
}